// Round 1
// baseline (584.711 us; speedup 1.0000x reference)
//
#include <hip/hip_runtime.h>

// Problem constants (from reference setup_inputs):
//   B=4, S=4096, H=512, K=2, D=8 devices, 64 experts
//   T = B*S = 16384
//   out: [D, T*K, H] fp32 = 8 * 32768 * 512 = 134,217,728 floats (512 MiB)
#define NDEV    8
#define TOK     16384
#define TOPK    2
#define HID     512
#define COLS    (HID / 4)          // 128 float4 per row
#define ROWS    (NDEV * TOK * TOPK)  // 262144
#define TOTAL4  (ROWS * COLS)        // 33,554,432 float4 elements

__global__ __launch_bounds__(256)
void a2a_dispatch_kernel(const float4* __restrict__ x,     // [TOK, COLS]
                         const int*    __restrict__ eidx,  // [TOK*TOPK]
                         const int*    __restrict__ emap,  // [64]
                         float4*       __restrict__ out)   // [ROWS, COLS]
{
    const int idx = blockIdx.x * blockDim.x + threadIdx.x;   // < TOTAL4 (fits i32)
    const int col = idx & (COLS - 1);
    const int row = idx >> 7;            // / COLS
    const int d   = row >> 15;           // / (TOK*TOPK) = /32768
    const int tk  = row & 32767;         // % 32768
    const int t   = tk >> 1;             // / TOPK

    // Wave-uniform per row: all 64 lanes of a wave share (d, tk).
    const int dev = emap[eidx[tk]];

    float4 v = make_float4(0.f, 0.f, 0.f, 0.f);
    if (dev == d) {
        v = x[t * COLS + col];
    }
    out[idx] = v;
}

extern "C" void kernel_launch(void* const* d_in, const int* in_sizes, int n_in,
                              void* d_out, int out_size, void* d_ws, size_t ws_size,
                              hipStream_t stream) {
    const float4* x    = (const float4*)d_in[0];   // input_tensor [4,4096,512] fp32
    const int*    eidx = (const int*)d_in[1];      // expert_indices [4,4096,2] int32
    const int*    emap = (const int*)d_in[2];      // expert_mapping [64] int32
    float4*       out  = (float4*)d_out;           // [8, 32768, 512] fp32

    const int block = 256;
    const int grid  = TOTAL4 / block;              // 131072 blocks
    a2a_dispatch_kernel<<<grid, block, 0, stream>>>(x, eidx, emap, out);
}

// Round 2
// 561.411 us; speedup vs baseline: 1.0415x; 1.0415x over previous
//
#include <hip/hip_runtime.h>

// B=4, S=4096, H=512, K=2, D=8, experts=64
// T = 16384 tokens; out: [8, 32768, 512] fp32 = 512 MiB
#define NDEV    8
#define TOK     16384
#define TKROWS  (TOK * 2)          // 32768 (token,k) rows
#define COLS    128                // float4 per row (H=512)
#define DSTRIDE (TKROWS * COLS)    // float4 elems per device section = 4,194,304

typedef float f4 __attribute__((ext_vector_type(4)));

__global__ __launch_bounds__(256)
void a2a_dispatch_kernel(const f4*  __restrict__ x,     // [TOK, COLS]
                         const int* __restrict__ eidx,  // [TKROWS]
                         const int* __restrict__ emap,  // [64]
                         f4*        __restrict__ out)   // [NDEV, TKROWS, COLS]
{
    const int idx = blockIdx.x * 256 + threadIdx.x;   // [0, TKROWS*COLS)
    const int col = idx & (COLS - 1);
    const int tk  = idx >> 7;
    const int t   = tk >> 1;                          // token id (K=2)

    // Wave-uniform: all 64 lanes of a wave share tk.
    const int dev = emap[eidx[tk]];                   // in [0, NDEV)

    const f4 v = x[t * COLS + col];
    const f4 z = {0.f, 0.f, 0.f, 0.f};

    // Write all 8 device slots for this (tk, col): one gets the token,
    // seven get zeros. 8 coalesced 1 KiB wave-stores, 64 MiB apart.
#pragma unroll
    for (int d = 0; d < NDEV; ++d) {
        f4 w = (d == dev) ? v : z;
        __builtin_nontemporal_store(w, out + (size_t)d * DSTRIDE + idx);
    }
}

extern "C" void kernel_launch(void* const* d_in, const int* in_sizes, int n_in,
                              void* d_out, int out_size, void* d_ws, size_t ws_size,
                              hipStream_t stream) {
    const f4*  x    = (const f4*)d_in[0];
    const int* eidx = (const int*)d_in[1];
    const int* emap = (const int*)d_in[2];
    f4*        out  = (f4*)d_out;

    const int block = 256;
    const int grid  = (TKROWS * COLS) / block;        // 16384 blocks
    a2a_dispatch_kernel<<<grid, block, 0, stream>>>(x, eidx, emap, out);
}

// Round 3
// 543.692 us; speedup vs baseline: 1.0754x; 1.0326x over previous
//
#include <hip/hip_runtime.h>

// B=4, S=4096, H=512, K=2, D=8, experts=64
// T = 16384 tokens; out: [8, 32768, 512] fp32 = 512 MiB
#define NDEV    8
#define TOK     16384
#define TKROWS  (TOK * 2)          // 32768 (token,k) rows
#define COLS    128                // float4 per row (H=512)
#define DSTRIDE (TKROWS * COLS)    // float4 elems per device section

typedef float f4 __attribute__((ext_vector_type(4)));

// Writes ONLY the non-zero slots: for each (tk, col), copy token row into
// its routed device section. 4.19M threads, 16 B load + 16 B store each.
// The 512 MiB zero background is laid down by hipMemsetAsync (rocclr fill
// kernel, measured at 6.24 TB/s on this buffer every round).
__global__ __launch_bounds__(256)
void a2a_scatter_kernel(const f4*  __restrict__ x,     // [TOK, COLS]
                        const int* __restrict__ eidx,  // [TKROWS]
                        const int* __restrict__ emap,  // [64]
                        f4*        __restrict__ out)   // [NDEV, TKROWS, COLS]
{
    const int idx = blockIdx.x * 256 + threadIdx.x;   // [0, TKROWS*COLS)
    const int col = idx & (COLS - 1);
    const int tk  = idx >> 7;
    const int t   = tk >> 1;                          // token id (K=2)

    // Wave-uniform per row (64 lanes span one half-row of one tk).
    const int dev = emap[eidx[tk]];                   // in [0, NDEV)

    // Coalesced 1 KiB wave-store into the routed device section.
    out[(size_t)dev * DSTRIDE + idx] = x[t * COLS + col];
}

extern "C" void kernel_launch(void* const* d_in, const int* in_sizes, int n_in,
                              void* d_out, int out_size, void* d_ws, size_t ws_size,
                              hipStream_t stream) {
    const f4*  x    = (const f4*)d_in[0];
    const int* eidx = (const int*)d_in[1];
    const int* emap = (const int*)d_in[2];
    f4*        out  = (f4*)d_out;

    // Zero background via the runtime fill path (graph-capture legal,
    // measured 6.24 TB/s): 512 MiB -> ~86 us.
    hipMemsetAsync(d_out, 0, (size_t)out_size * sizeof(float), stream);

    // Then scatter the 64 MiB of actual token data over it.
    const int block = 256;
    const int grid  = (TKROWS * COLS) / block;        // 16384 blocks
    a2a_scatter_kernel<<<grid, block, 0, stream>>>(x, eidx, emap, out);
}